// Round 15
// baseline (4001.014 us; speedup 1.0000x reference)
//
#include <hip/hip_runtime.h>

typedef unsigned short u16;
typedef unsigned int u32;
typedef __attribute__((ext_vector_type(8))) short short8;
typedef __attribute__((ext_vector_type(4))) float float4v;

static constexpr int   kN    = 100000;   // nodes
static constexpr int   kE    = 200000;   // edges
static constexpr int   kEMB  = 300;
static constexpr int   kSA   = 304;      // feature row stride (elems)
static constexpr int   kKW1  = 320;      // W1T row stride (K padded)
static constexpr int   kNH   = 600;
static constexpr int   kNHP  = 608;
static constexpr int   kNP2  = 304;
static constexpr int   kG    = 5000;
static constexpr int   kL    = 5;
static constexpr float kEPS  = 1e-5f;

// mlp pipeline LDS strides
static constexpr int   kSB1  = 328;      // B1 slice row stride (u16)
static constexpr int   kSB2  = 40;       // B2 slice row stride (u16)
static constexpr int   kSSCW = 36;       // scratch row stride (u32)

__device__ inline float bf2f(u16 u) {
    union { u32 u32v; float f; } v; v.u32v = ((u32)u) << 16; return v.f;
}
__device__ inline u16 f2bf(float f) {
    union { float f; u32 u; } v; v.f = f;
    u32 r = v.u + 0x7fff + ((v.u >> 16) & 1);
    return (u16)(r >> 16);
}
__device__ inline short8 load8(const u16* p) {
    return *reinterpret_cast<const short8*>(p);
}
__device__ inline void store8(u16* p, short8 v) {
    *reinterpret_cast<short8*>(p) = v;
}
__device__ inline float4v zed4() { float4v z = {0.f, 0.f, 0.f, 0.f}; return z; }
__device__ inline float gload(const void* p, long long i, int isf32) {
    if (isf32) return ((const float*)p)[i];
    return bf2f(((const u16*)p)[i]);
}
__device__ inline float pread(const void* p, size_t i, int f32p) {
    if (f32p) return ((const float*)p)[i];
    return bf2f(((const u16*)p)[i]);
}
__device__ inline void pwrite(void* p, size_t i, float v, int f32p) {
    if (f32p) ((float*)p)[i] = v;
    else      ((u16*)p)[i] = f2bf(v);
}

// ---- dtype detect: vote on W1 bit patterns --------------------------------
__global__ void detect_kernel(const u16* __restrict__ w1raw, int* flag) {
    if (threadIdx.x == 0 && blockIdx.x == 0) {
        int cnt = 0;
        for (int i = 0; i < 256; ++i) {
            int e = (w1raw[i] >> 7) & 0xFF;
            if (e >= 96 && e <= 126) ++cnt;
        }
        *flag = (cnt >= 200) ? 0 : 1;                // 0 = bf16 inputs, 1 = f32
    }
}

// ---- convert a float input to canonical f32 -------------------------------
__global__ void cvt_kernel(const void* __restrict__ src, float* __restrict__ dst,
                           int n, const int* __restrict__ flag) {
    int i = blockIdx.x * blockDim.x + threadIdx.x;
    if (i >= n) return;
    int isf = *flag;
    dst[i] = isf ? ((const float*)src)[i] : bf2f(((const u16*)src)[i]);
}

// ---- weight transpose + pad (bf16 out; writes every element) --------------
__global__ void w1t_kernel(const void* __restrict__ W1, u16* __restrict__ W1T,
                           const int* __restrict__ flag) {
    int idx = blockIdx.x * blockDim.x + threadIdx.x;
    const int per_layer = kNHP * kKW1;
    if (idx >= kL * per_layer) return;
    int isf = *flag;
    int l = idx / per_layer; int rem = idx - l * per_layer;
    int n = rem / kKW1; int k = rem - n * kKW1;
    u16 v = 0;
    if (n < kNH && k < kEMB)
        v = f2bf(gload(W1, (long long)l * kEMB * kNH + (long long)k * kNH + n, isf));
    W1T[idx] = v;
}
__global__ void w2t_kernel(const void* __restrict__ W2, u16* __restrict__ W2T,
                           const int* __restrict__ flag) {
    int idx = blockIdx.x * blockDim.x + threadIdx.x;
    const int per_layer = kNP2 * kNHP;
    if (idx >= kL * per_layer) return;
    int isf = *flag;
    int l = idx / per_layer; int rem = idx - l * per_layer;
    int n = rem / kNHP; int k = rem - n * kNHP;
    u16 v = 0;
    if (n < kEMB && k < kNH)
        v = f2bf(gload(W2, (long long)l * kNH * kEMB + (long long)k * kEMB + n, isf));
    W2T[idx] = v;
}

// ---- embedding: h = emb1[x0] + emb2[x1] -> plane --------------------------
__global__ void embed_kernel(const int* __restrict__ x,
                             const float* __restrict__ emb1,
                             const float* __restrict__ emb2,
                             void* __restrict__ h, int f32p) {
    int idx = blockIdx.x * blockDim.x + threadIdx.x;
    if (idx >= kN * kSA) return;
    int n = idx / kSA; int c = idx - n * kSA;
    float v = 0.f;
    if (c < kEMB) v = emb1[x[2 * n] * kEMB + c] + emb2[x[2 * n + 1] * kEMB + c];
    pwrite(h, idx, v, f32p);
}

// ---- CSR build ------------------------------------------------------------
__global__ void zero_int_kernel(int* p, int n) {
    int i = blockIdx.x * blockDim.x + threadIdx.x;
    if (i < n) p[i] = 0;
}
__global__ void zero_f32_kernel(float* p, int n) {
    int i = blockIdx.x * blockDim.x + threadIdx.x;
    if (i < n) p[i] = 0.f;
}
__global__ void count_kernel(const int* __restrict__ dst, int* row_ptr) {
    int e = blockIdx.x * blockDim.x + threadIdx.x;
    if (e < kE) atomicAdd(&row_ptr[1 + dst[e]], 1);
}
__global__ __launch_bounds__(1024) void scan_kernel(int* a, int n) {
    __shared__ int s[1024];
    __shared__ int carry;
    int t = threadIdx.x;
    if (t == 0) carry = 0;
    __syncthreads();
    for (int base = 0; base < n; base += 1024) {
        int i = base + t;
        s[t] = (i < n) ? a[i] : 0;
        __syncthreads();
        for (int off = 1; off < 1024; off <<= 1) {
            int v = (t >= off) ? s[t - off] : 0;
            __syncthreads();
            s[t] += v;
            __syncthreads();
        }
        if (i < n) a[i] = s[t] + carry;
        __syncthreads();
        if (t == 1023) carry += s[1023];
        __syncthreads();
    }
}
__global__ void scatter_kernel(const int* __restrict__ src, const int* __restrict__ dst,
                               const int* __restrict__ ea,
                               const int* __restrict__ row_ptr, int* cursor,
                               int* __restrict__ epack) {
    int e = blockIdx.x * blockDim.x + threadIdx.x;
    if (e >= kE) return;
    int d = dst[e];
    int pos = row_ptr[d] + atomicAdd(&cursor[d], 1);
    epack[pos] = src[e] | (ea[2 * e] << 20) | (ea[2 * e + 1] << 24);
}

// ---- BN coefficient hoist: sc/sh per column -------------------------------
__global__ void bn_coef_kernel(const float* __restrict__ stats,
                               const float* __restrict__ gam,
                               const float* __restrict__ bet,
                               float* __restrict__ coef) {
    int c = blockIdx.x * blockDim.x + threadIdx.x;
    if (c >= kEMB) return;
    const float invM = 1.0f / kN;
    float mu = stats[c] * invM;
    float var = stats[kEMB + c] * invM - mu * mu;
    if (var < 0.f) var = 0.f;
    float rs = rsqrtf(var + kEPS);
    float sc = rs * gam[c];
    coef[c] = sc;
    coef[kEMB + c] = bet[c] - mu * sc;
}

// ---- aggregation with fused BN(+relu), 4 NODES PER WAVE -------------------
// r14's +1-edge prefetch was neutral: with avg degree ~2 the per-node chain
// is too short; each wave had only ~6 loads in flight vs ~300cyc L2 latency.
// Now each wave walks 4 independent node edge-lists concurrently -> 4x the
// memory-level parallelism.  All masks are wave-uniform; per-node edge order
// unchanged -> bit-identical output.
__global__ __launch_bounds__(256) void aggregate_kernel(
        const void* __restrict__ h, const int* __restrict__ row_ptr,
        const int* __restrict__ epack,
        const float* __restrict__ e1,    // [6][kEMB] layer slice (f32)
        const float* __restrict__ e2,    // [3][kEMB]
        const float* __restrict__ coef,  // [2][kEMB] sc/sh (mode=1)
        void* __restrict__ agg, int mode, int f32p) {
    int wave = threadIdx.x >> 6;
    int lane = threadIdx.x & 63;
    int base = (blockIdx.x * 4 + wave) * 4;          // 4 nodes per wave

    float sc[5], sh[5];
#pragma unroll
    for (int j = 0; j < 5; ++j) {
        int c = j * 64 + lane;
        sc[j] = 1.f; sh[j] = 0.f;
        if (mode && c < kEMB) {
            sc[j] = coef[c];
            sh[j] = coef[kEMB + c];
        }
    }

    int s[4], e[4];
    float acc[4][5];
#pragma unroll
    for (int t = 0; t < 4; ++t) {
        int node = base + t;
        if (node < kN) { s[t] = row_ptr[node]; e[t] = row_ptr[node + 1]; }
        else           { s[t] = 0; e[t] = 0; }
#pragma unroll
        for (int j = 0; j < 5; ++j) {
            int c = j * 64 + lane;
            acc[t][j] = 0.f;
            if (node < kN && c < kEMB) {
                float hv = pread(h, (size_t)node * kSA + c, f32p) * sc[j] + sh[j];
                if (mode && hv < 0.f) hv = 0.f;
                acc[t][j] = hv + e1[c] + e2[c];      // self loop ea=(0,0)
            }
        }
    }

    int maxd = 0;
#pragma unroll
    for (int t = 0; t < 4; ++t) {
        int d = e[t] - s[t];
        if (d > maxd) maxd = d;
    }

    for (int i = 0; i < maxd; ++i) {
        int p[4], act[4];
#pragma unroll
        for (int t = 0; t < 4; ++t) {                // issue edge-record loads
            act[t] = (s[t] + i < e[t]);
            p[t] = act[t] ? epack[s[t] + i] : 0;
        }
        float hv[4][5];
#pragma unroll
        for (int t = 0; t < 4; ++t) {                // issue all gathers
            if (act[t]) {
                int srcn = p[t] & 0xFFFFF;
#pragma unroll
                for (int j = 0; j < 5; ++j) {
                    int c = j * 64 + lane;
                    hv[t][j] = (c < kEMB) ? pread(h, (size_t)srcn * kSA + c, f32p) : 0.f;
                }
            }
        }
#pragma unroll
        for (int t = 0; t < 4; ++t) {                // accumulate
            if (act[t]) {
                int a0 = (p[t] >> 20) & 15;
                int a1 = (p[t] >> 24) & 15;
#pragma unroll
                for (int j = 0; j < 5; ++j) {
                    int c = j * 64 + lane;
                    if (c < kEMB) {
                        float w = hv[t][j] * sc[j] + sh[j];
                        if (mode && w < 0.f) w = 0.f;
                        acc[t][j] += w + e1[a0 * kEMB + c] + e2[a1 * kEMB + c];
                    }
                }
            }
        }
    }

#pragma unroll
    for (int t = 0; t < 4; ++t) {
        int node = base + t;
        if (node < kN) {
#pragma unroll
            for (int j = 0; j < 5; ++j) {
                int c = j * 64 + lane;
                if (c < kSA)
                    pwrite(agg, (size_t)node * kSA + c, (c < kEMB) ? acc[t][j] : 0.f, f32p);
            }
        }
    }
}

// ---- fused MLP, k-slice pipeline v2 + FUSED BN STATS ----------------------
// r12-proven structure (240us).  New: the epilogue also computes per-column
// sum/sumsq of h2 via quad-shuffle reduction and atomicAdds into stats --
// deletes the bn_stats kernel (122MB re-read per layer).  Stats summation
// order changes (~1e-7 rel) -- harmless vs the 1.6x absmax margin.
template <int F32P>
__global__ __launch_bounds__(512, 2) void mlp_kernel(
        const void* A, void* D,           // may alias (small-ws): no restrict
        const u16* __restrict__ B1T,      // [kNHP][kKW1] bf16, zero-padded
        const float* __restrict__ bias1,  // [kNH] f32
        const u16* __restrict__ B2T,      // [kNP2][kNHP] bf16, zero-padded
        const float* __restrict__ bias2,  // [kEMB] f32
        float* __restrict__ stats) {      // [2][kEMB] zeroed before launch
    __shared__ u16 LB1[32 * kSB1];           // 20,992 B : B1T rows [32s,32s+32)
    __shared__ u16 LB2[304 * kSB2];          // 24,320 B : B2T cols [32s,32s+32)
    __shared__ u32 LSC[8][16 * kSSCW];       // 18,432 B : per-wave packed hi|lo
    int tid = threadIdx.x;
    int wave = tid >> 6, lane = tid & 63;
    int r16 = lane & 15, quad = lane >> 4;
    int mt_raw = blockIdx.x * 8 + wave;
    int mt = (mt_raw < kN / 16) ? mt_raw : (kN / 16 - 1);
    int valid = (mt_raw < kN / 16);

    // ---- A1 fragments (16 rows, hi/lo split when f32) ----
    short8 ahi[10], alo[10];
    short8 zed = {0, 0, 0, 0, 0, 0, 0, 0};
    if (F32P) {
        const float* Arow = (const float*)A + (size_t)(mt * 16 + r16) * kSA + quad * 8;
#pragma unroll
        for (int kc = 0; kc < 10; ++kc) {
            short8 h = zed, l = zed;
            if (kc < 9 || quad < 2) {
                const float* pp = Arow + kc * 32;
#pragma unroll
                for (int j = 0; j < 8; ++j) {
                    float xv = pp[j];
                    u16 hb = f2bf(xv);
                    float resid = xv - bf2f(hb);
                    h[j] = (short)hb;
                    l[j] = (short)f2bf(resid);
                }
            }
            ahi[kc] = h; alo[kc] = l;
        }
    } else {
        const u16* Arow = (const u16*)A + (size_t)(mt * 16 + r16) * kSA + quad * 8;
#pragma unroll
        for (int kc = 0; kc < 9; ++kc) ahi[kc] = load8(Arow + kc * 32);
        ahi[9] = (quad < 2) ? load8(Arow + 9 * 32) : zed;
#pragma unroll
        for (int kc = 0; kc < 10; ++kc) alo[kc] = zed;
    }

    // ---- persistent GEMM2 accumulators ----
    float4v acc2[19];
#pragma unroll
    for (int i = 0; i < 19; ++i) acc2[i] = zed4();

    u32* sc = &LSC[wave][0];

    // ---- staging registers + load/write helpers ----
    short8 st1[3], st2[3];
#pragma unroll
    for (int it = 0; it < 3; ++it) { st1[it] = zed; st2[it] = zed; }
    auto stage_load = [&](int s) {
#pragma unroll
        for (int it = 0; it < 3; ++it) {
            int f = (tid + it * 512) * 8;
            if (f < 32 * 320)
                st1[it] = load8(B1T + (size_t)(32 * s) * kKW1 + f);
        }
#pragma unroll
        for (int it = 0; it < 3; ++it) {
            int f = (tid + it * 512) * 8;
            if (f < 304 * 32) {
                int n = f >> 5, col = f & 31;
                st2[it] = load8(B2T + (size_t)n * kNHP + s * 32 + col);
            }
        }
    };
    auto stage_write = [&]() {
#pragma unroll
        for (int it = 0; it < 3; ++it) {
            int f = (tid + it * 512) * 8;
            if (f < 32 * 320) {
                int row = f / 320, col = f - row * 320;
                store8(&LB1[row * kSB1 + col], st1[it]);
            }
        }
#pragma unroll
        for (int it = 0; it < 3; ++it) {
            int f = (tid + it * 512) * 8;
            if (f < 304 * 32) {
                int n = f >> 5, col = f & 31;
                store8(&LB2[n * kSB2 + col], st2[it]);
            }
        }
    };

    stage_load(0);
    for (int s = 0; s < 19; ++s) {
        __syncthreads();   // prior slice's LB1/LB2 readers done
        stage_write();     // vmcnt wait here: loads issued one compute-phase ago
        __syncthreads();
        if (s + 1 < 19) stage_load(s + 1);   // overlap with compute below

        // ---- GEMM1 for nt1 = 2s, 2s+1 -> relu -> packed scratch ----
#pragma unroll
        for (int t = 0; t < 2; ++t) {
            const u16* bb = &LB1[(t * 16 + r16) * kSB1 + quad * 8];
            float4v acc = zed4();
#pragma unroll
            for (int kc = 0; kc < 10; ++kc) {
                short8 b = load8(bb + kc * 32);
                acc = __builtin_amdgcn_mfma_f32_16x16x32_bf16(ahi[kc], b, acc, 0, 0, 0);
                if (F32P)
                    acc = __builtin_amdgcn_mfma_f32_16x16x32_bf16(alo[kc], b, acc, 0, 0, 0);
            }
            int n = (2 * s + t) * 16 + r16;      // h1 col = lane&15
            float bv = (n < kNH) ? bias1[n] : 0.f;
#pragma unroll
            for (int r = 0; r < 4; ++r) {        // h1 row-in-tile = quad*4 + r
                float v = acc[r] + bv;
                if (v < 0.f) v = 0.f;
                u32 pk = 0;
                if (n < kNH) {
                    u16 hb = f2bf(v);
                    u16 lb = f2bf(v - bf2f(hb));
                    pk = (u32)hb | ((u32)lb << 16);
                }
                sc[(quad * 4 + r) * kSSCW + t * 16 + r16] = pk;
            }
        }
        // wave-private scratch: compiler inserts lgkmcnt wait before reads

        // ---- transpose read + unpack: A-layout frags for this k-slice ----
        u32 w0[8];
#pragma unroll
        for (int j = 0; j < 8; ++j) w0[j] = sc[r16 * kSSCW + quad * 8 + j];
        short8 a2h, a2l;
#pragma unroll
        for (int j = 0; j < 8; ++j) {
            a2h[j] = (short)(w0[j] & 0xFFFFu);
            a2l[j] = (short)(w0[j] >> 16);
        }

        // ---- GEMM2 accumulate (k-slice s) ----
#pragma unroll
        for (int nt2 = 0; nt2 < 19; ++nt2) {
            short8 b = load8(&LB2[(nt2 * 16 + r16) * kSB2 + quad * 8]);
            acc2[nt2] = __builtin_amdgcn_mfma_f32_16x16x32_bf16(a2h, b, acc2[nt2], 0, 0, 0);
            acc2[nt2] = __builtin_amdgcn_mfma_f32_16x16x32_bf16(a2l, b, acc2[nt2], 0, 0, 0);
        }
    }

    // ---- epilogue: +bias2 -> D, fused BN column sums ----
#pragma unroll
    for (int nt2 = 0; nt2 < 19; ++nt2) {
        int n = nt2 * 16 + r16;
        float s4 = 0.f, q4 = 0.f;
        if (n < kEMB) {
            float bv = bias2[n];
#pragma unroll
            for (int r = 0; r < 4; ++r) {
                float v = acc2[nt2][r] + bv;
                if (valid) {
                    int m = mt * 16 + quad * 4 + r;
                    pwrite(D, (size_t)m * kSA + n, v, F32P);
                }
                s4 += v; q4 += v * v;
            }
        }
        if (!valid) { s4 = 0.f; q4 = 0.f; }
        // reduce over the 4 quads holding column n
        s4 += __shfl_down(s4, 32); q4 += __shfl_down(q4, 32);
        s4 += __shfl_down(s4, 16); q4 += __shfl_down(q4, 16);
        if (quad == 0 && n < kEMB) {
            atomicAdd(&stats[n], s4);
            atomicAdd(&stats[kEMB + n], q4);
        }
    }
}

// ---- per-graph mean pool with fused final BN (no relu) --------------------
__device__ inline int lower_bound(const int* a, int n, int key) {
    int lo = 0, hi = n;
    while (lo < hi) { int mid = (lo + hi) >> 1; if (a[mid] < key) lo = mid + 1; else hi = mid; }
    return lo;
}
__global__ __launch_bounds__(64) void pool_kernel(const void* __restrict__ h2,
                                                  const int* __restrict__ batch,
                                                  const float* __restrict__ stats,
                                                  const float* __restrict__ gam,
                                                  const float* __restrict__ bet,
                                                  void* __restrict__ out,
                                                  const int* __restrict__ flag, int f32p) {
    int g = blockIdx.x;
    int lane = threadIdx.x;
    int isf = *flag;
    int start = lower_bound(batch, kN, g);
    int end = lower_bound(batch, kN, g + 1);
    int cnt = end - start;
    float inv = 1.0f / (float)(cnt > 0 ? cnt : 1);
    for (int c = lane; c < kEMB; c += 64) {
        const float invM = 1.0f / kN;
        float mu = stats[c] * invM;
        float var = stats[kEMB + c] * invM - mu * mu;
        if (var < 0.f) var = 0.f;
        float rs = rsqrtf(var + kEPS);
        float sc = rs * gam[c];
        float sh = bet[c] - mu * sc;
        float s = 0.f;
        for (int n = start; n < end; ++n)
            s += pread(h2, (size_t)n * kSA + c, f32p) * sc + sh;
        float v = s * inv;
        if (isf) ((float*)out)[g * kEMB + c] = v;
        else     ((u16*)out)[g * kEMB + c] = f2bf(v);
    }
}

// ===========================================================================
extern "C" void kernel_launch(void* const* d_in, const int* in_sizes, int n_in,
                              void* d_out, int out_size, void* d_ws, size_t ws_size,
                              hipStream_t stream) {
    const int* x          = (const int*)d_in[0];
    const int* edge_index = (const int*)d_in[1];
    const int* edge_attr  = (const int*)d_in[2];
    const int* batch      = (const int*)d_in[3];
    const void* x_emb1 = d_in[4];
    const void* x_emb2 = d_in[5];
    const void* e1raw  = d_in[6];
    const void* e2raw  = d_in[7];
    const void* W1     = d_in[8];
    const void* b1raw  = d_in[9];
    const void* W2     = d_in[10];
    const void* b2raw  = d_in[11];
    const void* gmraw  = d_in[12];
    const void* btraw  = d_in[13];

    const int* src = edge_index;
    const int* dst = edge_index + kE;

    // Path select: big ws -> f32 feature planes (high precision path).
    const int f32p = (ws_size >= (size_t)250000000) ? 1 : 0;
    const size_t esz = f32p ? 4 : 2;

    // ---- carve workspace (256B aligned) ----
    char* p = (char*)d_ws;
    size_t off = 0;
    auto carve = [&](size_t bytes) {
        void* r = p + off;
        off += (bytes + 255) & ~(size_t)255;
        return r;
    };
    void* plane0 = carve((size_t)kN * kSA * esz);
    void* plane1 = carve((size_t)kN * kSA * esz);
    u16* W1T     = (u16*)carve((size_t)kL * kNHP * kKW1 * 2);
    u16* W2T     = (u16*)carve((size_t)kL * kNP2 * kNHP * 2);
    int* row_ptr = (int*)carve((size_t)(kN + 1) * 4);
    int* cursor  = (int*)carve((size_t)kN * 4);
    int* epack   = (int*)carve((size_t)kE * 4);
    float* stats = (float*)carve(2 * kEMB * 4);
    float* coef  = (float*)carve(2 * kEMB * 4);
    int* flag    = (int*)carve(256);
    float* parf  = (float*)carve((size_t)57900 * 4);   // canonical f32 params

    float* emb1  = parf + 0;       // 36000
    float* emb2  = parf + 36000;   // 900
    float* e1    = parf + 36900;   // 9000
    float* e2    = parf + 45900;   // 4500
    float* b1    = parf + 50400;   // 3000
    float* b2    = parf + 53400;   // 1500
    float* gamma = parf + 54900;   // 1500
    float* beta  = parf + 56400;   // 1500

    // ---- dtype detect + canonicalize params to f32 ----
    detect_kernel<<<1, 64, 0, stream>>>((const u16*)W1, flag);
    cvt_kernel<<<(36000 + 255) / 256, 256, 0, stream>>>(x_emb1, emb1, 36000, flag);
    cvt_kernel<<<(900 + 255) / 256, 256, 0, stream>>>(x_emb2, emb2, 900, flag);
    cvt_kernel<<<(9000 + 255) / 256, 256, 0, stream>>>(e1raw, e1, 9000, flag);
    cvt_kernel<<<(4500 + 255) / 256, 256, 0, stream>>>(e2raw, e2, 4500, flag);
    cvt_kernel<<<(3000 + 255) / 256, 256, 0, stream>>>(b1raw, b1, 3000, flag);
    cvt_kernel<<<(1500 + 255) / 256, 256, 0, stream>>>(b2raw, b2, 1500, flag);
    cvt_kernel<<<(1500 + 255) / 256, 256, 0, stream>>>(gmraw, gamma, 1500, flag);
    cvt_kernel<<<(1500 + 255) / 256, 256, 0, stream>>>(btraw, beta, 1500, flag);

    // ---- weight transpose/pad (bf16) ----
    {
        int n1 = kL * kNHP * kKW1;
        w1t_kernel<<<(n1 + 255) / 256, 256, 0, stream>>>(W1, W1T, flag);
        int n2 = kL * kNP2 * kNHP;
        w2t_kernel<<<(n2 + 255) / 256, 256, 0, stream>>>(W2, W2T, flag);
    }

    // ---- embedding into plane0 ----
    embed_kernel<<<(kN * kSA + 255) / 256, 256, 0, stream>>>(x, emb1, emb2, plane0, f32p);

    // ---- CSR build ----
    zero_int_kernel<<<(kN + 1 + 255) / 256, 256, 0, stream>>>(row_ptr, kN + 1);
    zero_int_kernel<<<(kN + 255) / 256, 256, 0, stream>>>(cursor, kN);
    count_kernel<<<(kE + 255) / 256, 256, 0, stream>>>(dst, row_ptr);
    scan_kernel<<<1, 1024, 0, stream>>>(row_ptr + 1, kN);
    scatter_kernel<<<(kE + 255) / 256, 256, 0, stream>>>(src, dst, edge_attr, row_ptr,
                                                         cursor, epack);

    // ---- layers ----
    const int mlp_blocks = (kN / 16 + 7) / 8;   // 782 (8 m-tiles per block)
    const int agg_blocks = (kN + 15) / 16;      // 6250 (16 nodes per block)
    void* cur = plane0;
    void* agg = plane1;
    for (int l = 0; l < kL; ++l) {
        aggregate_kernel<<<agg_blocks, 256, 0, stream>>>(
            cur, row_ptr, epack, e1 + l * 6 * kEMB, e2 + l * 3 * kEMB,
            coef, agg, (l > 0) ? 1 : 0, f32p);
        void* dout = f32p ? cur : agg;
        zero_f32_kernel<<<(2 * kEMB + 255) / 256, 256, 0, stream>>>(stats, 2 * kEMB);
        if (f32p)
            mlp_kernel<1><<<mlp_blocks, 512, 0, stream>>>(
                agg, dout, W1T + (size_t)l * kNHP * kKW1, b1 + l * kNH,
                W2T + (size_t)l * kNP2 * kNHP, b2 + l * kEMB, stats);
        else
            mlp_kernel<0><<<mlp_blocks, 512, 0, stream>>>(
                agg, dout, W1T + (size_t)l * kNHP * kKW1, b1 + l * kNH,
                W2T + (size_t)l * kNP2 * kNHP, b2 + l * kEMB, stats);
        bn_coef_kernel<<<(kEMB + 255) / 256, 256, 0, stream>>>(
            stats, gamma + l * kEMB, beta + l * kEMB, coef);
        cur = dout;
        agg = (cur == plane0) ? plane1 : plane0;
    }

    // ---- pooling with fused final BN ----
    pool_kernel<<<kG, 64, 0, stream>>>(cur, batch, stats, gamma + 4 * kEMB,
                                       beta + 4 * kEMB, d_out, flag, f32p);
}

// Round 16
// 2279.279 us; speedup vs baseline: 1.7554x; 1.7554x over previous
//
#include <hip/hip_runtime.h>

typedef unsigned short u16;
typedef unsigned int u32;
typedef __attribute__((ext_vector_type(8))) short short8;
typedef __attribute__((ext_vector_type(4))) float float4v;

static constexpr int   kN    = 100000;   // nodes
static constexpr int   kE    = 200000;   // edges
static constexpr int   kEMB  = 300;
static constexpr int   kSA   = 304;      // feature row stride (elems)
static constexpr int   kKW1  = 320;      // W1T row stride (K padded)
static constexpr int   kNH   = 600;
static constexpr int   kNHP  = 608;
static constexpr int   kNP2  = 304;
static constexpr int   kG    = 5000;
static constexpr int   kL    = 5;
static constexpr float kEPS  = 1e-5f;

// mlp pipeline LDS strides
static constexpr int   kSB1  = 328;      // B1 slice row stride (u16)
static constexpr int   kSB2  = 40;       // B2 slice row stride (u16)
static constexpr int   kSSCW = 36;       // scratch row stride (u32)

__device__ inline float bf2f(u16 u) {
    union { u32 u32v; float f; } v; v.u32v = ((u32)u) << 16; return v.f;
}
__device__ inline u16 f2bf(float f) {
    union { float f; u32 u; } v; v.f = f;
    u32 r = v.u + 0x7fff + ((v.u >> 16) & 1);
    return (u16)(r >> 16);
}
__device__ inline short8 load8(const u16* p) {
    return *reinterpret_cast<const short8*>(p);
}
__device__ inline void store8(u16* p, short8 v) {
    *reinterpret_cast<short8*>(p) = v;
}
__device__ inline float4v zed4() { float4v z = {0.f, 0.f, 0.f, 0.f}; return z; }
__device__ inline float gload(const void* p, long long i, int isf32) {
    if (isf32) return ((const float*)p)[i];
    return bf2f(((const u16*)p)[i]);
}
__device__ inline float pread(const void* p, size_t i, int f32p) {
    if (f32p) return ((const float*)p)[i];
    return bf2f(((const u16*)p)[i]);
}
__device__ inline void pwrite(void* p, size_t i, float v, int f32p) {
    if (f32p) ((float*)p)[i] = v;
    else      ((u16*)p)[i] = f2bf(v);
}

// ---- dtype detect: vote on W1 bit patterns --------------------------------
__global__ void detect_kernel(const u16* __restrict__ w1raw, int* flag) {
    if (threadIdx.x == 0 && blockIdx.x == 0) {
        int cnt = 0;
        for (int i = 0; i < 256; ++i) {
            int e = (w1raw[i] >> 7) & 0xFF;
            if (e >= 96 && e <= 126) ++cnt;
        }
        *flag = (cnt >= 200) ? 0 : 1;                // 0 = bf16 inputs, 1 = f32
    }
}

// ---- convert a float input to canonical f32 -------------------------------
__global__ void cvt_kernel(const void* __restrict__ src, float* __restrict__ dst,
                           int n, const int* __restrict__ flag) {
    int i = blockIdx.x * blockDim.x + threadIdx.x;
    if (i >= n) return;
    int isf = *flag;
    dst[i] = isf ? ((const float*)src)[i] : bf2f(((const u16*)src)[i]);
}

// ---- weight transpose + pad (bf16 out; writes every element) --------------
__global__ void w1t_kernel(const void* __restrict__ W1, u16* __restrict__ W1T,
                           const int* __restrict__ flag) {
    int idx = blockIdx.x * blockDim.x + threadIdx.x;
    const int per_layer = kNHP * kKW1;
    if (idx >= kL * per_layer) return;
    int isf = *flag;
    int l = idx / per_layer; int rem = idx - l * per_layer;
    int n = rem / kKW1; int k = rem - n * kKW1;
    u16 v = 0;
    if (n < kNH && k < kEMB)
        v = f2bf(gload(W1, (long long)l * kEMB * kNH + (long long)k * kNH + n, isf));
    W1T[idx] = v;
}
__global__ void w2t_kernel(const void* __restrict__ W2, u16* __restrict__ W2T,
                           const int* __restrict__ flag) {
    int idx = blockIdx.x * blockDim.x + threadIdx.x;
    const int per_layer = kNP2 * kNHP;
    if (idx >= kL * per_layer) return;
    int isf = *flag;
    int l = idx / per_layer; int rem = idx - l * per_layer;
    int n = rem / kNHP; int k = rem - n * kNHP;
    u16 v = 0;
    if (n < kEMB && k < kNH)
        v = f2bf(gload(W2, (long long)l * kNH * kEMB + (long long)k * kEMB + n, isf));
    W2T[idx] = v;
}

// ---- embedding: h = emb1[x0] + emb2[x1] -> plane --------------------------
__global__ void embed_kernel(const int* __restrict__ x,
                             const float* __restrict__ emb1,
                             const float* __restrict__ emb2,
                             void* __restrict__ h, int f32p) {
    int idx = blockIdx.x * blockDim.x + threadIdx.x;
    if (idx >= kN * kSA) return;
    int n = idx / kSA; int c = idx - n * kSA;
    float v = 0.f;
    if (c < kEMB) v = emb1[x[2 * n] * kEMB + c] + emb2[x[2 * n + 1] * kEMB + c];
    pwrite(h, idx, v, f32p);
}

// ---- CSR build ------------------------------------------------------------
__global__ void zero_int_kernel(int* p, int n) {
    int i = blockIdx.x * blockDim.x + threadIdx.x;
    if (i < n) p[i] = 0;
}
__global__ void zero_f32_kernel(float* p, int n) {
    int i = blockIdx.x * blockDim.x + threadIdx.x;
    if (i < n) p[i] = 0.f;
}
__global__ void count_kernel(const int* __restrict__ dst, int* row_ptr) {
    int e = blockIdx.x * blockDim.x + threadIdx.x;
    if (e < kE) atomicAdd(&row_ptr[1 + dst[e]], 1);
}
__global__ __launch_bounds__(1024) void scan_kernel(int* a, int n) {
    __shared__ int s[1024];
    __shared__ int carry;
    int t = threadIdx.x;
    if (t == 0) carry = 0;
    __syncthreads();
    for (int base = 0; base < n; base += 1024) {
        int i = base + t;
        s[t] = (i < n) ? a[i] : 0;
        __syncthreads();
        for (int off = 1; off < 1024; off <<= 1) {
            int v = (t >= off) ? s[t - off] : 0;
            __syncthreads();
            s[t] += v;
            __syncthreads();
        }
        if (i < n) a[i] = s[t] + carry;
        __syncthreads();
        if (t == 1023) carry += s[1023];
        __syncthreads();
    }
}
__global__ void scatter_kernel(const int* __restrict__ src, const int* __restrict__ dst,
                               const int* __restrict__ ea,
                               const int* __restrict__ row_ptr, int* cursor,
                               int* __restrict__ epack) {
    int e = blockIdx.x * blockDim.x + threadIdx.x;
    if (e >= kE) return;
    int d = dst[e];
    int pos = row_ptr[d] + atomicAdd(&cursor[d], 1);
    epack[pos] = src[e] | (ea[2 * e] << 20) | (ea[2 * e + 1] << 24);
}

// ---- BN coefficient hoist: sc/sh per column -------------------------------
__global__ void bn_coef_kernel(const float* __restrict__ stats,
                               const float* __restrict__ gam,
                               const float* __restrict__ bet,
                               float* __restrict__ coef) {
    int c = blockIdx.x * blockDim.x + threadIdx.x;
    if (c >= kEMB) return;
    const float invM = 1.0f / kN;
    float mu = stats[c] * invM;
    float var = stats[kEMB + c] * invM - mu * mu;
    if (var < 0.f) var = 0.f;
    float rs = rsqrtf(var + kEPS);
    float sc = rs * gam[c];
    coef[c] = sc;
    coef[kEMB + c] = bet[c] - mu * sc;
}

// ---- aggregation with fused BN(+relu), 4 NODES PER WAVE (r15-proven) ------
__global__ __launch_bounds__(256) void aggregate_kernel(
        const void* __restrict__ h, const int* __restrict__ row_ptr,
        const int* __restrict__ epack,
        const float* __restrict__ e1,    // [6][kEMB] layer slice (f32)
        const float* __restrict__ e2,    // [3][kEMB]
        const float* __restrict__ coef,  // [2][kEMB] sc/sh (mode=1)
        void* __restrict__ agg, int mode, int f32p) {
    int wave = threadIdx.x >> 6;
    int lane = threadIdx.x & 63;
    int base = (blockIdx.x * 4 + wave) * 4;          // 4 nodes per wave

    float sc[5], sh[5];
#pragma unroll
    for (int j = 0; j < 5; ++j) {
        int c = j * 64 + lane;
        sc[j] = 1.f; sh[j] = 0.f;
        if (mode && c < kEMB) {
            sc[j] = coef[c];
            sh[j] = coef[kEMB + c];
        }
    }

    int s[4], e[4];
    float acc[4][5];
#pragma unroll
    for (int t = 0; t < 4; ++t) {
        int node = base + t;
        if (node < kN) { s[t] = row_ptr[node]; e[t] = row_ptr[node + 1]; }
        else           { s[t] = 0; e[t] = 0; }
#pragma unroll
        for (int j = 0; j < 5; ++j) {
            int c = j * 64 + lane;
            acc[t][j] = 0.f;
            if (node < kN && c < kEMB) {
                float hv = pread(h, (size_t)node * kSA + c, f32p) * sc[j] + sh[j];
                if (mode && hv < 0.f) hv = 0.f;
                acc[t][j] = hv + e1[c] + e2[c];      // self loop ea=(0,0)
            }
        }
    }

    int maxd = 0;
#pragma unroll
    for (int t = 0; t < 4; ++t) {
        int d = e[t] - s[t];
        if (d > maxd) maxd = d;
    }

    for (int i = 0; i < maxd; ++i) {
        int p[4], act[4];
#pragma unroll
        for (int t = 0; t < 4; ++t) {                // issue edge-record loads
            act[t] = (s[t] + i < e[t]);
            p[t] = act[t] ? epack[s[t] + i] : 0;
        }
        float hv[4][5];
#pragma unroll
        for (int t = 0; t < 4; ++t) {                // issue all gathers
            if (act[t]) {
                int srcn = p[t] & 0xFFFFF;
#pragma unroll
                for (int j = 0; j < 5; ++j) {
                    int c = j * 64 + lane;
                    hv[t][j] = (c < kEMB) ? pread(h, (size_t)srcn * kSA + c, f32p) : 0.f;
                }
            }
        }
#pragma unroll
        for (int t = 0; t < 4; ++t) {                // accumulate
            if (act[t]) {
                int a0 = (p[t] >> 20) & 15;
                int a1 = (p[t] >> 24) & 15;
#pragma unroll
                for (int j = 0; j < 5; ++j) {
                    int c = j * 64 + lane;
                    if (c < kEMB) {
                        float w = hv[t][j] * sc[j] + sh[j];
                        if (mode && w < 0.f) w = 0.f;
                        acc[t][j] += w + e1[a0 * kEMB + c] + e2[a1 * kEMB + c];
                    }
                }
            }
        }
    }

#pragma unroll
    for (int t = 0; t < 4; ++t) {
        int node = base + t;
        if (node < kN) {
#pragma unroll
            for (int j = 0; j < 5; ++j) {
                int c = j * 64 + lane;
                if (c < kSA)
                    pwrite(agg, (size_t)node * kSA + c, (c < kEMB) ? acc[t][j] : 0.f, f32p);
            }
        }
    }
}

// ---- fused MLP + BN stats with BLOCK-LEVEL reduction ----------------------
// r15 lesson: per-wave atomics (3.8M lane-atomics / 600 addrs) serialized
// ~460us per dispatch.  Now: per-wave partials -> LDS (reuse LB1 after the
// slice loop) -> one atomicAdd per column per block (469K total, 8x less).
// bn_stats kernel stays deleted.  GEMM math unchanged -> h2 bit-identical;
// stats order changes only within f32 sums (r15 showed absmax unaffected).
template <int F32P>
__global__ __launch_bounds__(512, 2) void mlp_kernel(
        const void* A, void* D,           // may alias (small-ws): no restrict
        const u16* __restrict__ B1T,      // [kNHP][kKW1] bf16, zero-padded
        const float* __restrict__ bias1,  // [kNH] f32
        const u16* __restrict__ B2T,      // [kNP2][kNHP] bf16, zero-padded
        const float* __restrict__ bias2,  // [kEMB] f32
        float* __restrict__ stats) {      // [2][kEMB] zeroed before launch
    __shared__ u16 LB1[32 * kSB1];           // 20,992 B : B1T rows [32s,32s+32)
    __shared__ u16 LB2[304 * kSB2];          // 24,320 B : B2T cols [32s,32s+32)
    __shared__ u32 LSC[8][16 * kSSCW];       // 18,432 B : per-wave packed hi|lo
    int tid = threadIdx.x;
    int wave = tid >> 6, lane = tid & 63;
    int r16 = lane & 15, quad = lane >> 4;
    int mt_raw = blockIdx.x * 8 + wave;
    int mt = (mt_raw < kN / 16) ? mt_raw : (kN / 16 - 1);
    int valid = (mt_raw < kN / 16);

    // ---- A1 fragments (16 rows, hi/lo split when f32) ----
    short8 ahi[10], alo[10];
    short8 zed = {0, 0, 0, 0, 0, 0, 0, 0};
    if (F32P) {
        const float* Arow = (const float*)A + (size_t)(mt * 16 + r16) * kSA + quad * 8;
#pragma unroll
        for (int kc = 0; kc < 10; ++kc) {
            short8 h = zed, l = zed;
            if (kc < 9 || quad < 2) {
                const float* pp = Arow + kc * 32;
#pragma unroll
                for (int j = 0; j < 8; ++j) {
                    float xv = pp[j];
                    u16 hb = f2bf(xv);
                    float resid = xv - bf2f(hb);
                    h[j] = (short)hb;
                    l[j] = (short)f2bf(resid);
                }
            }
            ahi[kc] = h; alo[kc] = l;
        }
    } else {
        const u16* Arow = (const u16*)A + (size_t)(mt * 16 + r16) * kSA + quad * 8;
#pragma unroll
        for (int kc = 0; kc < 9; ++kc) ahi[kc] = load8(Arow + kc * 32);
        ahi[9] = (quad < 2) ? load8(Arow + 9 * 32) : zed;
#pragma unroll
        for (int kc = 0; kc < 10; ++kc) alo[kc] = zed;
    }

    // ---- persistent GEMM2 accumulators ----
    float4v acc2[19];
#pragma unroll
    for (int i = 0; i < 19; ++i) acc2[i] = zed4();

    u32* sc = &LSC[wave][0];

    // ---- staging registers + load/write helpers ----
    short8 st1[3], st2[3];
#pragma unroll
    for (int it = 0; it < 3; ++it) { st1[it] = zed; st2[it] = zed; }
    auto stage_load = [&](int s) {
#pragma unroll
        for (int it = 0; it < 3; ++it) {
            int f = (tid + it * 512) * 8;
            if (f < 32 * 320)
                st1[it] = load8(B1T + (size_t)(32 * s) * kKW1 + f);
        }
#pragma unroll
        for (int it = 0; it < 3; ++it) {
            int f = (tid + it * 512) * 8;
            if (f < 304 * 32) {
                int n = f >> 5, col = f & 31;
                st2[it] = load8(B2T + (size_t)n * kNHP + s * 32 + col);
            }
        }
    };
    auto stage_write = [&]() {
#pragma unroll
        for (int it = 0; it < 3; ++it) {
            int f = (tid + it * 512) * 8;
            if (f < 32 * 320) {
                int row = f / 320, col = f - row * 320;
                store8(&LB1[row * kSB1 + col], st1[it]);
            }
        }
#pragma unroll
        for (int it = 0; it < 3; ++it) {
            int f = (tid + it * 512) * 8;
            if (f < 304 * 32) {
                int n = f >> 5, col = f & 31;
                store8(&LB2[n * kSB2 + col], st2[it]);
            }
        }
    };

    stage_load(0);
    for (int s = 0; s < 19; ++s) {
        __syncthreads();   // prior slice's LB1/LB2 readers done
        stage_write();     // vmcnt wait here: loads issued one compute-phase ago
        __syncthreads();
        if (s + 1 < 19) stage_load(s + 1);   // overlap with compute below

        // ---- GEMM1 for nt1 = 2s, 2s+1 -> relu -> packed scratch ----
#pragma unroll
        for (int t = 0; t < 2; ++t) {
            const u16* bb = &LB1[(t * 16 + r16) * kSB1 + quad * 8];
            float4v acc = zed4();
#pragma unroll
            for (int kc = 0; kc < 10; ++kc) {
                short8 b = load8(bb + kc * 32);
                acc = __builtin_amdgcn_mfma_f32_16x16x32_bf16(ahi[kc], b, acc, 0, 0, 0);
                if (F32P)
                    acc = __builtin_amdgcn_mfma_f32_16x16x32_bf16(alo[kc], b, acc, 0, 0, 0);
            }
            int n = (2 * s + t) * 16 + r16;      // h1 col = lane&15
            float bv = (n < kNH) ? bias1[n] : 0.f;
#pragma unroll
            for (int r = 0; r < 4; ++r) {        // h1 row-in-tile = quad*4 + r
                float v = acc[r] + bv;
                if (v < 0.f) v = 0.f;
                u32 pk = 0;
                if (n < kNH) {
                    u16 hb = f2bf(v);
                    u16 lb = f2bf(v - bf2f(hb));
                    pk = (u32)hb | ((u32)lb << 16);
                }
                sc[(quad * 4 + r) * kSSCW + t * 16 + r16] = pk;
            }
        }
        // wave-private scratch: compiler inserts lgkmcnt wait before reads

        // ---- transpose read + unpack: A-layout frags for this k-slice ----
        u32 w0[8];
#pragma unroll
        for (int j = 0; j < 8; ++j) w0[j] = sc[r16 * kSSCW + quad * 8 + j];
        short8 a2h, a2l;
#pragma unroll
        for (int j = 0; j < 8; ++j) {
            a2h[j] = (short)(w0[j] & 0xFFFFu);
            a2l[j] = (short)(w0[j] >> 16);
        }

        // ---- GEMM2 accumulate (k-slice s) ----
#pragma unroll
        for (int nt2 = 0; nt2 < 19; ++nt2) {
            short8 b = load8(&LB2[(nt2 * 16 + r16) * kSB2 + quad * 8]);
            acc2[nt2] = __builtin_amdgcn_mfma_f32_16x16x32_bf16(a2h, b, acc2[nt2], 0, 0, 0);
            acc2[nt2] = __builtin_amdgcn_mfma_f32_16x16x32_bf16(a2l, b, acc2[nt2], 0, 0, 0);
        }
    }

    // ---- epilogue: +bias2 -> D; block-level BN stat reduction ----
    __syncthreads();                 // all waves done reading LB1/LB2
    float* RB = (float*)LB1;         // reuse: 5248 floats >= 2*8*304
#pragma unroll
    for (int nt2 = 0; nt2 < 19; ++nt2) {
        int n = nt2 * 16 + r16;
        float s4 = 0.f, q4 = 0.f;
        if (valid && n < kEMB) {
            float bv = bias2[n];
#pragma unroll
            for (int r = 0; r < 4; ++r) {
                float v = acc2[nt2][r] + bv;
                int m = mt * 16 + quad * 4 + r;
                pwrite(D, (size_t)m * kSA + n, v, F32P);
                s4 += v; q4 += v * v;
            }
        }
        // reduce over the 4 quads holding column n
        s4 += __shfl_down(s4, 32); q4 += __shfl_down(q4, 32);
        s4 += __shfl_down(s4, 16); q4 += __shfl_down(q4, 16);
        if (quad == 0) {
            RB[wave * 304 + nt2 * 16 + r16] = s4;
            RB[2432 + wave * 304 + nt2 * 16 + r16] = q4;
        }
    }
    __syncthreads();
    for (int c = tid; c < 304; c += 512) {
        if (c < kEMB) {
            float ss = 0.f, qq = 0.f;
#pragma unroll
            for (int w = 0; w < 8; ++w) {
                ss += RB[w * 304 + c];
                qq += RB[2432 + w * 304 + c];
            }
            atomicAdd(&stats[c], ss);
            atomicAdd(&stats[kEMB + c], qq);
        }
    }
}

// ---- per-graph mean pool with fused final BN (no relu) --------------------
__device__ inline int lower_bound(const int* a, int n, int key) {
    int lo = 0, hi = n;
    while (lo < hi) { int mid = (lo + hi) >> 1; if (a[mid] < key) lo = mid + 1; else hi = mid; }
    return lo;
}
__global__ __launch_bounds__(64) void pool_kernel(const void* __restrict__ h2,
                                                  const int* __restrict__ batch,
                                                  const float* __restrict__ stats,
                                                  const float* __restrict__ gam,
                                                  const float* __restrict__ bet,
                                                  void* __restrict__ out,
                                                  const int* __restrict__ flag, int f32p) {
    int g = blockIdx.x;
    int lane = threadIdx.x;
    int isf = *flag;
    int start = lower_bound(batch, kN, g);
    int end = lower_bound(batch, kN, g + 1);
    int cnt = end - start;
    float inv = 1.0f / (float)(cnt > 0 ? cnt : 1);
    for (int c = lane; c < kEMB; c += 64) {
        const float invM = 1.0f / kN;
        float mu = stats[c] * invM;
        float var = stats[kEMB + c] * invM - mu * mu;
        if (var < 0.f) var = 0.f;
        float rs = rsqrtf(var + kEPS);
        float sc = rs * gam[c];
        float sh = bet[c] - mu * sc;
        float s = 0.f;
        for (int n = start; n < end; ++n)
            s += pread(h2, (size_t)n * kSA + c, f32p) * sc + sh;
        float v = s * inv;
        if (isf) ((float*)out)[g * kEMB + c] = v;
        else     ((u16*)out)[g * kEMB + c] = f2bf(v);
    }
}

// ===========================================================================
extern "C" void kernel_launch(void* const* d_in, const int* in_sizes, int n_in,
                              void* d_out, int out_size, void* d_ws, size_t ws_size,
                              hipStream_t stream) {
    const int* x          = (const int*)d_in[0];
    const int* edge_index = (const int*)d_in[1];
    const int* edge_attr  = (const int*)d_in[2];
    const int* batch      = (const int*)d_in[3];
    const void* x_emb1 = d_in[4];
    const void* x_emb2 = d_in[5];
    const void* e1raw  = d_in[6];
    const void* e2raw  = d_in[7];
    const void* W1     = d_in[8];
    const void* b1raw  = d_in[9];
    const void* W2     = d_in[10];
    const void* b2raw  = d_in[11];
    const void* gmraw  = d_in[12];
    const void* btraw  = d_in[13];

    const int* src = edge_index;
    const int* dst = edge_index + kE;

    // Path select: big ws -> f32 feature planes (high precision path).
    const int f32p = (ws_size >= (size_t)250000000) ? 1 : 0;
    const size_t esz = f32p ? 4 : 2;

    // ---- carve workspace (256B aligned) ----
    char* p = (char*)d_ws;
    size_t off = 0;
    auto carve = [&](size_t bytes) {
        void* r = p + off;
        off += (bytes + 255) & ~(size_t)255;
        return r;
    };
    void* plane0 = carve((size_t)kN * kSA * esz);
    void* plane1 = carve((size_t)kN * kSA * esz);
    u16* W1T     = (u16*)carve((size_t)kL * kNHP * kKW1 * 2);
    u16* W2T     = (u16*)carve((size_t)kL * kNP2 * kNHP * 2);
    int* row_ptr = (int*)carve((size_t)(kN + 1) * 4);
    int* cursor  = (int*)carve((size_t)kN * 4);
    int* epack   = (int*)carve((size_t)kE * 4);
    float* stats = (float*)carve(2 * kEMB * 4);
    float* coef  = (float*)carve(2 * kEMB * 4);
    int* flag    = (int*)carve(256);
    float* parf  = (float*)carve((size_t)57900 * 4);   // canonical f32 params

    float* emb1  = parf + 0;       // 36000
    float* emb2  = parf + 36000;   // 900
    float* e1    = parf + 36900;   // 9000
    float* e2    = parf + 45900;   // 4500
    float* b1    = parf + 50400;   // 3000
    float* b2    = parf + 53400;   // 1500
    float* gamma = parf + 54900;   // 1500
    float* beta  = parf + 56400;   // 1500

    // ---- dtype detect + canonicalize params to f32 ----
    detect_kernel<<<1, 64, 0, stream>>>((const u16*)W1, flag);
    cvt_kernel<<<(36000 + 255) / 256, 256, 0, stream>>>(x_emb1, emb1, 36000, flag);
    cvt_kernel<<<(900 + 255) / 256, 256, 0, stream>>>(x_emb2, emb2, 900, flag);
    cvt_kernel<<<(9000 + 255) / 256, 256, 0, stream>>>(e1raw, e1, 9000, flag);
    cvt_kernel<<<(4500 + 255) / 256, 256, 0, stream>>>(e2raw, e2, 4500, flag);
    cvt_kernel<<<(3000 + 255) / 256, 256, 0, stream>>>(b1raw, b1, 3000, flag);
    cvt_kernel<<<(1500 + 255) / 256, 256, 0, stream>>>(b2raw, b2, 1500, flag);
    cvt_kernel<<<(1500 + 255) / 256, 256, 0, stream>>>(gmraw, gamma, 1500, flag);
    cvt_kernel<<<(1500 + 255) / 256, 256, 0, stream>>>(btraw, beta, 1500, flag);

    // ---- weight transpose/pad (bf16) ----
    {
        int n1 = kL * kNHP * kKW1;
        w1t_kernel<<<(n1 + 255) / 256, 256, 0, stream>>>(W1, W1T, flag);
        int n2 = kL * kNP2 * kNHP;
        w2t_kernel<<<(n2 + 255) / 256, 256, 0, stream>>>(W2, W2T, flag);
    }

    // ---- embedding into plane0 ----
    embed_kernel<<<(kN * kSA + 255) / 256, 256, 0, stream>>>(x, emb1, emb2, plane0, f32p);

    // ---- CSR build ----
    zero_int_kernel<<<(kN + 1 + 255) / 256, 256, 0, stream>>>(row_ptr, kN + 1);
    zero_int_kernel<<<(kN + 255) / 256, 256, 0, stream>>>(cursor, kN);
    count_kernel<<<(kE + 255) / 256, 256, 0, stream>>>(dst, row_ptr);
    scan_kernel<<<1, 1024, 0, stream>>>(row_ptr + 1, kN);
    scatter_kernel<<<(kE + 255) / 256, 256, 0, stream>>>(src, dst, edge_attr, row_ptr,
                                                         cursor, epack);

    // ---- layers ----
    const int mlp_blocks = (kN / 16 + 7) / 8;   // 782 (8 m-tiles per block)
    const int agg_blocks = (kN + 15) / 16;      // 6250 (16 nodes per block)
    void* cur = plane0;
    void* agg = plane1;
    for (int l = 0; l < kL; ++l) {
        aggregate_kernel<<<agg_blocks, 256, 0, stream>>>(
            cur, row_ptr, epack, e1 + l * 6 * kEMB, e2 + l * 3 * kEMB,
            coef, agg, (l > 0) ? 1 : 0, f32p);
        void* dout = f32p ? cur : agg;
        zero_f32_kernel<<<(2 * kEMB + 255) / 256, 256, 0, stream>>>(stats, 2 * kEMB);
        if (f32p)
            mlp_kernel<1><<<mlp_blocks, 512, 0, stream>>>(
                agg, dout, W1T + (size_t)l * kNHP * kKW1, b1 + l * kNH,
                W2T + (size_t)l * kNP2 * kNHP, b2 + l * kEMB, stats);
        else
            mlp_kernel<0><<<mlp_blocks, 512, 0, stream>>>(
                agg, dout, W1T + (size_t)l * kNHP * kKW1, b1 + l * kNH,
                W2T + (size_t)l * kNP2 * kNHP, b2 + l * kEMB, stats);
        bn_coef_kernel<<<(kEMB + 255) / 256, 256, 0, stream>>>(
            stats, gamma + l * kEMB, beta + l * kEMB, coef);
        cur = dout;
        agg = (cur == plane0) ? plane1 : plane0;
    }

    // ---- pooling with fused final BN ----
    pool_kernel<<<kG, 64, 0, stream>>>(cur, batch, stats, gamma + 4 * kEMB,
                                       beta + 4 * kEMB, d_out, flag, f32p);
}

// Round 17
// 2105.832 us; speedup vs baseline: 1.9000x; 1.0824x over previous
//
#include <hip/hip_runtime.h>

typedef unsigned short u16;
typedef unsigned int u32;
typedef __attribute__((ext_vector_type(8))) short short8;
typedef __attribute__((ext_vector_type(4))) float float4v;

static constexpr int   kN    = 100000;   // nodes
static constexpr int   kE    = 200000;   // edges
static constexpr int   kEMB  = 300;
static constexpr int   kSA   = 304;      // feature row stride (elems)
static constexpr int   kKW1  = 320;      // W1T row stride (K padded)
static constexpr int   kNH   = 600;
static constexpr int   kNHP  = 608;
static constexpr int   kNP2  = 304;
static constexpr int   kG    = 5000;
static constexpr int   kL    = 5;
static constexpr float kEPS  = 1e-5f;

// mlp pipeline LDS strides
static constexpr int   kSB1  = 328;      // B1 slice row stride (u16)
static constexpr int   kSB2  = 40;       // B2 slice row stride (u16)
static constexpr int   kSSCW = 36;       // scratch row stride (u32)

__device__ inline float bf2f(u16 u) {
    union { u32 u32v; float f; } v; v.u32v = ((u32)u) << 16; return v.f;
}
__device__ inline u16 f2bf(float f) {
    union { float f; u32 u; } v; v.f = f;
    u32 r = v.u + 0x7fff + ((v.u >> 16) & 1);
    return (u16)(r >> 16);
}
__device__ inline short8 load8(const u16* p) {
    return *reinterpret_cast<const short8*>(p);
}
__device__ inline void store8(u16* p, short8 v) {
    *reinterpret_cast<short8*>(p) = v;
}
__device__ inline float4v zed4() { float4v z = {0.f, 0.f, 0.f, 0.f}; return z; }
__device__ inline float gload(const void* p, long long i, int isf32) {
    if (isf32) return ((const float*)p)[i];
    return bf2f(((const u16*)p)[i]);
}
__device__ inline float pread(const void* p, size_t i, int f32p) {
    if (f32p) return ((const float*)p)[i];
    return bf2f(((const u16*)p)[i]);
}
__device__ inline void pwrite(void* p, size_t i, float v, int f32p) {
    if (f32p) ((float*)p)[i] = v;
    else      ((u16*)p)[i] = f2bf(v);
}

// ---- dtype detect: vote on W1 bit patterns --------------------------------
__global__ void detect_kernel(const u16* __restrict__ w1raw, int* flag) {
    if (threadIdx.x == 0 && blockIdx.x == 0) {
        int cnt = 0;
        for (int i = 0; i < 256; ++i) {
            int e = (w1raw[i] >> 7) & 0xFF;
            if (e >= 96 && e <= 126) ++cnt;
        }
        *flag = (cnt >= 200) ? 0 : 1;                // 0 = bf16 inputs, 1 = f32
    }
}

// ---- convert a float input to canonical f32 -------------------------------
__global__ void cvt_kernel(const void* __restrict__ src, float* __restrict__ dst,
                           int n, const int* __restrict__ flag) {
    int i = blockIdx.x * blockDim.x + threadIdx.x;
    if (i >= n) return;
    int isf = *flag;
    dst[i] = isf ? ((const float*)src)[i] : bf2f(((const u16*)src)[i]);
}

// ---- weight transpose + pad (bf16 out; writes every element) --------------
__global__ void w1t_kernel(const void* __restrict__ W1, u16* __restrict__ W1T,
                           const int* __restrict__ flag) {
    int idx = blockIdx.x * blockDim.x + threadIdx.x;
    const int per_layer = kNHP * kKW1;
    if (idx >= kL * per_layer) return;
    int isf = *flag;
    int l = idx / per_layer; int rem = idx - l * per_layer;
    int n = rem / kKW1; int k = rem - n * kKW1;
    u16 v = 0;
    if (n < kNH && k < kEMB)
        v = f2bf(gload(W1, (long long)l * kEMB * kNH + (long long)k * kNH + n, isf));
    W1T[idx] = v;
}
__global__ void w2t_kernel(const void* __restrict__ W2, u16* __restrict__ W2T,
                           const int* __restrict__ flag) {
    int idx = blockIdx.x * blockDim.x + threadIdx.x;
    const int per_layer = kNP2 * kNHP;
    if (idx >= kL * per_layer) return;
    int isf = *flag;
    int l = idx / per_layer; int rem = idx - l * per_layer;
    int n = rem / kNHP; int k = rem - n * kNHP;
    u16 v = 0;
    if (n < kEMB && k < kNH)
        v = f2bf(gload(W2, (long long)l * kNH * kEMB + (long long)k * kEMB + n, isf));
    W2T[idx] = v;
}

// ---- embedding: h = emb1[x0] + emb2[x1] -> plane --------------------------
__global__ void embed_kernel(const int* __restrict__ x,
                             const float* __restrict__ emb1,
                             const float* __restrict__ emb2,
                             void* __restrict__ h, int f32p) {
    int idx = blockIdx.x * blockDim.x + threadIdx.x;
    if (idx >= kN * kSA) return;
    int n = idx / kSA; int c = idx - n * kSA;
    float v = 0.f;
    if (c < kEMB) v = emb1[x[2 * n] * kEMB + c] + emb2[x[2 * n + 1] * kEMB + c];
    pwrite(h, idx, v, f32p);
}

// ---- CSR build ------------------------------------------------------------
__global__ void zero_int_kernel(int* p, int n) {
    int i = blockIdx.x * blockDim.x + threadIdx.x;
    if (i < n) p[i] = 0;
}
__global__ void count_kernel(const int* __restrict__ dst, int* row_ptr) {
    int e = blockIdx.x * blockDim.x + threadIdx.x;
    if (e < kE) atomicAdd(&row_ptr[1 + dst[e]], 1);
}
// multi-block scan: phase 1 — per-1024-block inclusive scan, block sums out
__global__ __launch_bounds__(1024) void scan1_kernel(int* a, int* bsum, int n) {
    __shared__ int s[1024];
    int t = threadIdx.x;
    int i = blockIdx.x * 1024 + t;
    s[t] = (i < n) ? a[i] : 0;
    __syncthreads();
    for (int off = 1; off < 1024; off <<= 1) {
        int v = (t >= off) ? s[t - off] : 0;
        __syncthreads();
        s[t] += v;
        __syncthreads();
    }
    if (i < n) a[i] = s[t];
    if (t == 1023) bsum[blockIdx.x] = s[t];
}
// phase 2 — exclusive scan of block sums (nb <= 128)
__global__ __launch_bounds__(128) void scan2_kernel(const int* bsum, int* ebsum, int nb) {
    __shared__ int s[128];
    int t = threadIdx.x;
    int orig = (t < nb) ? bsum[t] : 0;
    s[t] = orig;
    __syncthreads();
    for (int off = 1; off < 128; off <<= 1) {
        int v = (t >= off) ? s[t - off] : 0;
        __syncthreads();
        s[t] += v;
        __syncthreads();
    }
    if (t < nb) ebsum[t] = s[t] - orig;   // exclusive
}
// phase 3 — add block offsets (in place over a = row_ptr+1), set row_ptr[0]
__global__ void scan3_kernel(int* a, const int* ebsum, int* row_ptr0, int n) {
    int i = blockIdx.x * blockDim.x + threadIdx.x;
    if (i >= n) return;
    a[i] += ebsum[i >> 10];
    if (i == 0) *row_ptr0 = 0;
}
__global__ void scatter_kernel(const int* __restrict__ src, const int* __restrict__ dst,
                               const int* __restrict__ ea,
                               const int* __restrict__ row_ptr, int* cursor,
                               int* __restrict__ epack) {
    int e = blockIdx.x * blockDim.x + threadIdx.x;
    if (e >= kE) return;
    int d = dst[e];
    int pos = row_ptr[d] + atomicAdd(&cursor[d], 1);
    epack[pos] = src[e] | (ea[2 * e] << 20) | (ea[2 * e + 1] << 24);
}

// ---- aggregation, 4 NODES PER WAVE (r15-proven), now self-contained BN ----
// Computes sc/sh in-wave from prev layer's stats (same f32 expression as the
// old bn_coef kernel -> identical values); block 0 zeroes the NEXT stats
// buffer (consumed only by the following mlp launch -> no race).
__global__ __launch_bounds__(256) void aggregate_kernel(
        const void* __restrict__ h, const int* __restrict__ row_ptr,
        const int* __restrict__ epack,
        const float* __restrict__ e1,    // [6][kEMB] layer slice (f32)
        const float* __restrict__ e2,    // [3][kEMB]
        const float* __restrict__ stats_prev,  // prev layer stats (mode=1)
        const float* __restrict__ gam,         // prev layer gamma
        const float* __restrict__ bet,         // prev layer beta
        float* __restrict__ stats_next,        // zeroed here for next mlp
        void* __restrict__ agg, int mode, int f32p) {
    if (blockIdx.x == 0) {
        for (int i = threadIdx.x; i < 2 * kEMB; i += 256) stats_next[i] = 0.f;
    }
    int wave = threadIdx.x >> 6;
    int lane = threadIdx.x & 63;
    int base = (blockIdx.x * 4 + wave) * 4;          // 4 nodes per wave

    float sc[5], sh[5];
#pragma unroll
    for (int j = 0; j < 5; ++j) {
        int c = j * 64 + lane;
        sc[j] = 1.f; sh[j] = 0.f;
        if (mode && c < kEMB) {
            const float invM = 1.0f / kN;
            float mu = stats_prev[c] * invM;
            float var = stats_prev[kEMB + c] * invM - mu * mu;
            if (var < 0.f) var = 0.f;
            float rs = rsqrtf(var + kEPS);
            sc[j] = rs * gam[c];
            sh[j] = bet[c] - mu * sc[j];
        }
    }

    int s[4], e[4];
    float acc[4][5];
#pragma unroll
    for (int t = 0; t < 4; ++t) {
        int node = base + t;
        if (node < kN) { s[t] = row_ptr[node]; e[t] = row_ptr[node + 1]; }
        else           { s[t] = 0; e[t] = 0; }
#pragma unroll
        for (int j = 0; j < 5; ++j) {
            int c = j * 64 + lane;
            acc[t][j] = 0.f;
            if (node < kN && c < kEMB) {
                float hv = pread(h, (size_t)node * kSA + c, f32p) * sc[j] + sh[j];
                if (mode && hv < 0.f) hv = 0.f;
                acc[t][j] = hv + e1[c] + e2[c];      // self loop ea=(0,0)
            }
        }
    }

    int maxd = 0;
#pragma unroll
    for (int t = 0; t < 4; ++t) {
        int d = e[t] - s[t];
        if (d > maxd) maxd = d;
    }

    for (int i = 0; i < maxd; ++i) {
        int p[4], act[4];
#pragma unroll
        for (int t = 0; t < 4; ++t) {                // issue edge-record loads
            act[t] = (s[t] + i < e[t]);
            p[t] = act[t] ? epack[s[t] + i] : 0;
        }
        float hv[4][5];
#pragma unroll
        for (int t = 0; t < 4; ++t) {                // issue all gathers
            if (act[t]) {
                int srcn = p[t] & 0xFFFFF;
#pragma unroll
                for (int j = 0; j < 5; ++j) {
                    int c = j * 64 + lane;
                    hv[t][j] = (c < kEMB) ? pread(h, (size_t)srcn * kSA + c, f32p) : 0.f;
                }
            }
        }
#pragma unroll
        for (int t = 0; t < 4; ++t) {                // accumulate
            if (act[t]) {
                int a0 = (p[t] >> 20) & 15;
                int a1 = (p[t] >> 24) & 15;
#pragma unroll
                for (int j = 0; j < 5; ++j) {
                    int c = j * 64 + lane;
                    if (c < kEMB) {
                        float w = hv[t][j] * sc[j] + sh[j];
                        if (mode && w < 0.f) w = 0.f;
                        acc[t][j] += w + e1[a0 * kEMB + c] + e2[a1 * kEMB + c];
                    }
                }
            }
        }
    }

#pragma unroll
    for (int t = 0; t < 4; ++t) {
        int node = base + t;
        if (node < kN) {
#pragma unroll
            for (int j = 0; j < 5; ++j) {
                int c = j * 64 + lane;
                if (c < kSA)
                    pwrite(agg, (size_t)node * kSA + c, (c < kEMB) ? acc[t][j] : 0.f, f32p);
            }
        }
    }
}

// ---- fused MLP + BN stats with block-level reduction (r16-proven) ---------
template <int F32P>
__global__ __launch_bounds__(512, 2) void mlp_kernel(
        const void* A, void* D,           // may alias (small-ws): no restrict
        const u16* __restrict__ B1T,      // [kNHP][kKW1] bf16, zero-padded
        const float* __restrict__ bias1,  // [kNH] f32
        const u16* __restrict__ B2T,      // [kNP2][kNHP] bf16, zero-padded
        const float* __restrict__ bias2,  // [kEMB] f32
        float* __restrict__ stats) {      // [2][kEMB] zeroed by prior aggregate
    __shared__ u16 LB1[32 * kSB1];           // 20,992 B : B1T rows [32s,32s+32)
    __shared__ u16 LB2[304 * kSB2];          // 24,320 B : B2T cols [32s,32s+32)
    __shared__ u32 LSC[8][16 * kSSCW];       // 18,432 B : per-wave packed hi|lo
    int tid = threadIdx.x;
    int wave = tid >> 6, lane = tid & 63;
    int r16 = lane & 15, quad = lane >> 4;
    int mt_raw = blockIdx.x * 8 + wave;
    int mt = (mt_raw < kN / 16) ? mt_raw : (kN / 16 - 1);
    int valid = (mt_raw < kN / 16);

    // ---- A1 fragments (16 rows, hi/lo split when f32) ----
    short8 ahi[10], alo[10];
    short8 zed = {0, 0, 0, 0, 0, 0, 0, 0};
    if (F32P) {
        const float* Arow = (const float*)A + (size_t)(mt * 16 + r16) * kSA + quad * 8;
#pragma unroll
        for (int kc = 0; kc < 10; ++kc) {
            short8 h = zed, l = zed;
            if (kc < 9 || quad < 2) {
                const float* pp = Arow + kc * 32;
#pragma unroll
                for (int j = 0; j < 8; ++j) {
                    float xv = pp[j];
                    u16 hb = f2bf(xv);
                    float resid = xv - bf2f(hb);
                    h[j] = (short)hb;
                    l[j] = (short)f2bf(resid);
                }
            }
            ahi[kc] = h; alo[kc] = l;
        }
    } else {
        const u16* Arow = (const u16*)A + (size_t)(mt * 16 + r16) * kSA + quad * 8;
#pragma unroll
        for (int kc = 0; kc < 9; ++kc) ahi[kc] = load8(Arow + kc * 32);
        ahi[9] = (quad < 2) ? load8(Arow + 9 * 32) : zed;
#pragma unroll
        for (int kc = 0; kc < 10; ++kc) alo[kc] = zed;
    }

    // ---- persistent GEMM2 accumulators ----
    float4v acc2[19];
#pragma unroll
    for (int i = 0; i < 19; ++i) acc2[i] = zed4();

    u32* sc = &LSC[wave][0];

    // ---- staging registers + load/write helpers ----
    short8 st1[3], st2[3];
#pragma unroll
    for (int it = 0; it < 3; ++it) { st1[it] = zed; st2[it] = zed; }
    auto stage_load = [&](int s) {
#pragma unroll
        for (int it = 0; it < 3; ++it) {
            int f = (tid + it * 512) * 8;
            if (f < 32 * 320)
                st1[it] = load8(B1T + (size_t)(32 * s) * kKW1 + f);
        }
#pragma unroll
        for (int it = 0; it < 3; ++it) {
            int f = (tid + it * 512) * 8;
            if (f < 304 * 32) {
                int n = f >> 5, col = f & 31;
                st2[it] = load8(B2T + (size_t)n * kNHP + s * 32 + col);
            }
        }
    };
    auto stage_write = [&]() {
#pragma unroll
        for (int it = 0; it < 3; ++it) {
            int f = (tid + it * 512) * 8;
            if (f < 32 * 320) {
                int row = f / 320, col = f - row * 320;
                store8(&LB1[row * kSB1 + col], st1[it]);
            }
        }
#pragma unroll
        for (int it = 0; it < 3; ++it) {
            int f = (tid + it * 512) * 8;
            if (f < 304 * 32) {
                int n = f >> 5, col = f & 31;
                store8(&LB2[n * kSB2 + col], st2[it]);
            }
        }
    };

    stage_load(0);
    for (int s = 0; s < 19; ++s) {
        __syncthreads();   // prior slice's LB1/LB2 readers done
        stage_write();     // vmcnt wait here: loads issued one compute-phase ago
        __syncthreads();
        if (s + 1 < 19) stage_load(s + 1);   // overlap with compute below

        // ---- GEMM1 for nt1 = 2s, 2s+1 -> relu -> packed scratch ----
#pragma unroll
        for (int t = 0; t < 2; ++t) {
            const u16* bb = &LB1[(t * 16 + r16) * kSB1 + quad * 8];
            float4v acc = zed4();
#pragma unroll
            for (int kc = 0; kc < 10; ++kc) {
                short8 b = load8(bb + kc * 32);
                acc = __builtin_amdgcn_mfma_f32_16x16x32_bf16(ahi[kc], b, acc, 0, 0, 0);
                if (F32P)
                    acc = __builtin_amdgcn_mfma_f32_16x16x32_bf16(alo[kc], b, acc, 0, 0, 0);
            }
            int n = (2 * s + t) * 16 + r16;      // h1 col = lane&15
            float bv = (n < kNH) ? bias1[n] : 0.f;
#pragma unroll
            for (int r = 0; r < 4; ++r) {        // h1 row-in-tile = quad*4 + r
                float v = acc[r] + bv;
                if (v < 0.f) v = 0.f;
                u32 pk = 0;
                if (n < kNH) {
                    u16 hb = f2bf(v);
                    u16 lb = f2bf(v - bf2f(hb));
                    pk = (u32)hb | ((u32)lb << 16);
                }
                sc[(quad * 4 + r) * kSSCW + t * 16 + r16] = pk;
            }
        }
        // wave-private scratch: compiler inserts lgkmcnt wait before reads

        // ---- transpose read + unpack: A-layout frags for this k-slice ----
        u32 w0[8];
#pragma unroll
        for (int j = 0; j < 8; ++j) w0[j] = sc[r16 * kSSCW + quad * 8 + j];
        short8 a2h, a2l;
#pragma unroll
        for (int j = 0; j < 8; ++j) {
            a2h[j] = (short)(w0[j] & 0xFFFFu);
            a2l[j] = (short)(w0[j] >> 16);
        }

        // ---- GEMM2 accumulate (k-slice s) ----
#pragma unroll
        for (int nt2 = 0; nt2 < 19; ++nt2) {
            short8 b = load8(&LB2[(nt2 * 16 + r16) * kSB2 + quad * 8]);
            acc2[nt2] = __builtin_amdgcn_mfma_f32_16x16x32_bf16(a2h, b, acc2[nt2], 0, 0, 0);
            acc2[nt2] = __builtin_amdgcn_mfma_f32_16x16x32_bf16(a2l, b, acc2[nt2], 0, 0, 0);
        }
    }

    // ---- epilogue: +bias2 -> D; block-level BN stat reduction ----
    __syncthreads();                 // all waves done reading LB1/LB2
    float* RB = (float*)LB1;         // reuse: 5248 floats >= 2*8*304
#pragma unroll
    for (int nt2 = 0; nt2 < 19; ++nt2) {
        int n = nt2 * 16 + r16;
        float s4 = 0.f, q4 = 0.f;
        if (valid && n < kEMB) {
            float bv = bias2[n];
#pragma unroll
            for (int r = 0; r < 4; ++r) {
                float v = acc2[nt2][r] + bv;
                int m = mt * 16 + quad * 4 + r;
                pwrite(D, (size_t)m * kSA + n, v, F32P);
                s4 += v; q4 += v * v;
            }
        }
        // reduce over the 4 quads holding column n
        s4 += __shfl_down(s4, 32); q4 += __shfl_down(q4, 32);
        s4 += __shfl_down(s4, 16); q4 += __shfl_down(q4, 16);
        if (quad == 0) {
            RB[wave * 304 + nt2 * 16 + r16] = s4;
            RB[2432 + wave * 304 + nt2 * 16 + r16] = q4;
        }
    }
    __syncthreads();
    for (int c = tid; c < 304; c += 512) {
        if (c < kEMB) {
            float ss = 0.f, qq = 0.f;
#pragma unroll
            for (int w = 0; w < 8; ++w) {
                ss += RB[w * 304 + c];
                qq += RB[2432 + w * 304 + c];
            }
            atomicAdd(&stats[c], ss);
            atomicAdd(&stats[kEMB + c], qq);
        }
    }
}

// ---- per-graph mean pool with fused final BN (no relu) --------------------
__device__ inline int lower_bound(const int* a, int n, int key) {
    int lo = 0, hi = n;
    while (lo < hi) { int mid = (lo + hi) >> 1; if (a[mid] < key) lo = mid + 1; else hi = mid; }
    return lo;
}
__global__ __launch_bounds__(64) void pool_kernel(const void* __restrict__ h2,
                                                  const int* __restrict__ batch,
                                                  const float* __restrict__ stats,
                                                  const float* __restrict__ gam,
                                                  const float* __restrict__ bet,
                                                  void* __restrict__ out,
                                                  const int* __restrict__ flag, int f32p) {
    int g = blockIdx.x;
    int lane = threadIdx.x;
    int isf = *flag;
    int start = lower_bound(batch, kN, g);
    int end = lower_bound(batch, kN, g + 1);
    int cnt = end - start;
    float inv = 1.0f / (float)(cnt > 0 ? cnt : 1);
    for (int c = lane; c < kEMB; c += 64) {
        const float invM = 1.0f / kN;
        float mu = stats[c] * invM;
        float var = stats[kEMB + c] * invM - mu * mu;
        if (var < 0.f) var = 0.f;
        float rs = rsqrtf(var + kEPS);
        float sc = rs * gam[c];
        float sh = bet[c] - mu * sc;
        float s = 0.f;
        for (int n = start; n < end; ++n)
            s += pread(h2, (size_t)n * kSA + c, f32p) * sc + sh;
        float v = s * inv;
        if (isf) ((float*)out)[g * kEMB + c] = v;
        else     ((u16*)out)[g * kEMB + c] = f2bf(v);
    }
}

// ===========================================================================
extern "C" void kernel_launch(void* const* d_in, const int* in_sizes, int n_in,
                              void* d_out, int out_size, void* d_ws, size_t ws_size,
                              hipStream_t stream) {
    const int* x          = (const int*)d_in[0];
    const int* edge_index = (const int*)d_in[1];
    const int* edge_attr  = (const int*)d_in[2];
    const int* batch      = (const int*)d_in[3];
    const void* x_emb1 = d_in[4];
    const void* x_emb2 = d_in[5];
    const void* e1raw  = d_in[6];
    const void* e2raw  = d_in[7];
    const void* W1     = d_in[8];
    const void* b1raw  = d_in[9];
    const void* W2     = d_in[10];
    const void* b2raw  = d_in[11];
    const void* gmraw  = d_in[12];
    const void* btraw  = d_in[13];

    const int* src = edge_index;
    const int* dst = edge_index + kE;

    // Path select: big ws -> f32 feature planes (high precision path).
    const int f32p = (ws_size >= (size_t)250000000) ? 1 : 0;
    const size_t esz = f32p ? 4 : 2;

    // ---- carve workspace (256B aligned) ----
    char* p = (char*)d_ws;
    size_t off = 0;
    auto carve = [&](size_t bytes) {
        void* r = p + off;
        off += (bytes + 255) & ~(size_t)255;
        return r;
    };
    void* plane0 = carve((size_t)kN * kSA * esz);
    void* plane1 = carve((size_t)kN * kSA * esz);
    u16* W1T     = (u16*)carve((size_t)kL * kNHP * kKW1 * 2);
    u16* W2T     = (u16*)carve((size_t)kL * kNP2 * kNHP * 2);
    int* row_ptr = (int*)carve((size_t)(kN + 1) * 4);
    int* cursor  = (int*)carve((size_t)kN * 4);
    int* epack   = (int*)carve((size_t)kE * 4);
    float* statsA = (float*)carve(2 * kEMB * 4);
    float* statsB = (float*)carve(2 * kEMB * 4);
    int* bsum    = (int*)carve(512);
    int* ebsum   = (int*)carve(512);
    int* flag    = (int*)carve(256);
    float* parf  = (float*)carve((size_t)57900 * 4);   // canonical f32 params

    float* emb1  = parf + 0;       // 36000
    float* emb2  = parf + 36000;   // 900
    float* e1    = parf + 36900;   // 9000
    float* e2    = parf + 45900;   // 4500
    float* b1    = parf + 50400;   // 3000
    float* b2    = parf + 53400;   // 1500
    float* gamma = parf + 54900;   // 1500
    float* beta  = parf + 56400;   // 1500

    // ---- dtype detect + canonicalize params to f32 ----
    detect_kernel<<<1, 64, 0, stream>>>((const u16*)W1, flag);
    cvt_kernel<<<(36000 + 255) / 256, 256, 0, stream>>>(x_emb1, emb1, 36000, flag);
    cvt_kernel<<<(900 + 255) / 256, 256, 0, stream>>>(x_emb2, emb2, 900, flag);
    cvt_kernel<<<(9000 + 255) / 256, 256, 0, stream>>>(e1raw, e1, 9000, flag);
    cvt_kernel<<<(4500 + 255) / 256, 256, 0, stream>>>(e2raw, e2, 4500, flag);
    cvt_kernel<<<(3000 + 255) / 256, 256, 0, stream>>>(b1raw, b1, 3000, flag);
    cvt_kernel<<<(1500 + 255) / 256, 256, 0, stream>>>(b2raw, b2, 1500, flag);
    cvt_kernel<<<(1500 + 255) / 256, 256, 0, stream>>>(gmraw, gamma, 1500, flag);
    cvt_kernel<<<(1500 + 255) / 256, 256, 0, stream>>>(btraw, beta, 1500, flag);

    // ---- weight transpose/pad (bf16) ----
    {
        int n1 = kL * kNHP * kKW1;
        w1t_kernel<<<(n1 + 255) / 256, 256, 0, stream>>>(W1, W1T, flag);
        int n2 = kL * kNP2 * kNHP;
        w2t_kernel<<<(n2 + 255) / 256, 256, 0, stream>>>(W2, W2T, flag);
    }

    // ---- embedding into plane0 ----
    embed_kernel<<<(kN * kSA + 255) / 256, 256, 0, stream>>>(x, emb1, emb2, plane0, f32p);

    // ---- CSR build (multi-block scan) ----
    zero_int_kernel<<<(kN + 1 + 255) / 256, 256, 0, stream>>>(row_ptr, kN + 1);
    zero_int_kernel<<<(kN + 255) / 256, 256, 0, stream>>>(cursor, kN);
    count_kernel<<<(kE + 255) / 256, 256, 0, stream>>>(dst, row_ptr);
    const int nb = (kN + 1023) / 1024;   // 98
    scan1_kernel<<<nb, 1024, 0, stream>>>(row_ptr + 1, bsum, kN);
    scan2_kernel<<<1, 128, 0, stream>>>(bsum, ebsum, nb);
    scan3_kernel<<<(kN + 255) / 256, 256, 0, stream>>>(row_ptr + 1, ebsum, row_ptr, kN);
    scatter_kernel<<<(kE + 255) / 256, 256, 0, stream>>>(src, dst, edge_attr, row_ptr,
                                                         cursor, epack);

    // ---- layers (stats ping-pong; no bn_coef / zero launches) ----
    const int mlp_blocks = (kN / 16 + 7) / 8;   // 782 (8 m-tiles per block)
    const int agg_blocks = (kN + 15) / 16;      // 6250 (16 nodes per block)
    void* cur = plane0;
    void* agg = plane1;
    float* stats_prev = statsA;   // unused at l=0
    for (int l = 0; l < kL; ++l) {
        float* stats_cur = (l % 2 == 0) ? statsA : statsB;
        const float* gam_prev = gamma + (l > 0 ? (l - 1) : 0) * kEMB;
        const float* bet_prev = beta + (l > 0 ? (l - 1) : 0) * kEMB;
        aggregate_kernel<<<agg_blocks, 256, 0, stream>>>(
            cur, row_ptr, epack, e1 + l * 6 * kEMB, e2 + l * 3 * kEMB,
            (l > 0) ? stats_prev : stats_cur, gam_prev, bet_prev,
            stats_cur, agg, (l > 0) ? 1 : 0, f32p);
        void* dout = f32p ? cur : agg;
        if (f32p)
            mlp_kernel<1><<<mlp_blocks, 512, 0, stream>>>(
                agg, dout, W1T + (size_t)l * kNHP * kKW1, b1 + l * kNH,
                W2T + (size_t)l * kNP2 * kNHP, b2 + l * kEMB, stats_cur);
        else
            mlp_kernel<0><<<mlp_blocks, 512, 0, stream>>>(
                agg, dout, W1T + (size_t)l * kNHP * kKW1, b1 + l * kNH,
                W2T + (size_t)l * kNP2 * kNHP, b2 + l * kEMB, stats_cur);
        stats_prev = stats_cur;
        cur = dout;
        agg = (cur == plane0) ? plane1 : plane0;
    }

    // ---- pooling with fused final BN (stats_prev = layer 4's stats) ----
    pool_kernel<<<kG, 64, 0, stream>>>(cur, batch, stats_prev, gamma + 4 * kEMB,
                                       beta + 4 * kEMB, d_out, flag, f32p);
}